// Round 13
// baseline (197.708 us; speedup 1.0000x reference)
//
#include <hip/hip_runtime.h>
#include <math.h>

#define TB 16
#define TL 8192
#define TC 64

constexpr float INV_BL = 1.0f / (16.0f * 8192.0f);
constexpr float EPSV = 1e-5f;
constexpr float INV_SQRT_H = 0.17677669529663687f; // 1/sqrt(32)

// workspace offsets (floats) — ws is 256 MiB
#define WS_G      0        /* [16][64][64] */
#define WS_SX     65536    /* [16][64] */
#define WS_STATS  66560    /* s1[64] d1[64] s2[64] d2[64] */
#define WS_M      66816    /* [16][64][64] */
#define WS_N      132352   /* [16][64][64] */
#define WS_S1T    197888   /* [16][64][256] -> ends 460032 */
#define WS_V1P    460032   /* [16][16jp][64c][256i] -> ends 4654336 */
#define WS_GPART  4654336  /* [16][64][4096] -> ends 8848640 */
#define WS_SXPART 8848640  /* [16][64][64] -> ends 8914176 */
#define WS_MPART  8914176  /* [16][16][4096] -> ends 9962752 */
#define WS_BAR    9962752  /* 8 ints (grid barrier counters) */

typedef __attribute__((ext_vector_type(8))) short short8v;  // 8 bf16 (4 VGPRs)
typedef __attribute__((ext_vector_type(4))) float f32x4;    // MFMA C/D

__device__ __forceinline__ ushort bf16rne(float f){
  uint u = __float_as_uint(f);
  u += 0x7FFF + ((u >> 16) & 1);
  return (ushort)(u >> 16);
}

__device__ __forceinline__ int fraddr(int ch, int g){
  return ch*128 + 8*(g ^ (ch & 7));
}

// device-scope grid barrier: 256 blocks, counters zeroed by k1 each launch
__device__ __forceinline__ void gridbar(float* ws, int phase){
  __syncthreads();
  if (threadIdx.x == 0){
    int* bar = (int*)(ws + WS_BAR);
    __threadfence();
    atomicAdd(&bar[phase], 1);
    while (__hip_atomic_load(&bar[phase], __ATOMIC_ACQUIRE, __HIP_MEMORY_SCOPE_AGENT) < 256){
      __builtin_amdgcn_s_sleep(8);
    }
    __threadfence();
  }
  __syncthreads();
}

// ---------------- K1 v7: single-shot MFMA Gram, 1024 blocks (R12-proven) ----------------
__global__ __launch_bounds__(256) void k1_gram(const float* __restrict__ x,
                                               float* __restrict__ ws){
  __shared__ ushort Xh[64*128];
  __shared__ ushort Xl[64*128];
  const int b = blockIdx.y, chunk = blockIdx.x;
  const int t = threadIdx.x;
  if (chunk==0 && b==0 && t<8) ((int*)(ws + WS_BAR))[t] = 0;  // reset grid-barrier
  const int lane = t & 63;
  const int w = __builtin_amdgcn_readfirstlane(t >> 6);  // wave 0..3
  const float* xb = x + (size_t)b*TC*TL + (size_t)chunk*128;
  const int ch = t >> 2, q = t & 3;
  float sx = 0.f;
  #pragma unroll
  for (int gg=0; gg<4; ++gg){
    const float4 v0 = *(const float4*)(xb + ch*TL + q*32 + 8*gg);
    const float4 v1 = *(const float4*)(xb + ch*TL + q*32 + 8*gg + 4);
    const float ff[8] = {v0.x,v0.y,v0.z,v0.w,v1.x,v1.y,v1.z,v1.w};
    union { short8v v; ushort u[8]; } hh, ll;
    #pragma unroll
    for (int i=0;i<8;++i){
      sx += ff[i];
      const ushort hv = bf16rne(ff[i]);
      hh.u[i] = hv;
      ll.u[i] = bf16rne(ff[i] - __uint_as_float(((uint)hv)<<16));
    }
    const int g = q*4 + gg;
    const int wa = ch*128 + 8*(g ^ (ch & 7));
    *(short8v*)&Xh[wa] = hh.v;
    *(short8v*)&Xl[wa] = ll.v;
  }
  __syncthreads();
  const int rA = w*16 + (lane & 15);
  const int gq = lane >> 4;
  f32x4 acc0={0.f,0.f,0.f,0.f}, acc1={0.f,0.f,0.f,0.f},
        acc2={0.f,0.f,0.f,0.f}, acc3={0.f,0.f,0.f,0.f};
  #pragma unroll
  for (int kk=0; kk<4; ++kk){
    const int g = kk*4 + gq;
    const short8v Ah = *(const short8v*)&Xh[fraddr(rA, g)];
    const short8v Al = *(const short8v*)&Xl[fraddr(rA, g)];
    const int rB = (lane & 15);
    const short8v Bh0 = *(const short8v*)&Xh[fraddr(rB,      g)];
    const short8v Bl0 = *(const short8v*)&Xl[fraddr(rB,      g)];
    const short8v Bh1 = *(const short8v*)&Xh[fraddr(rB + 16, g)];
    const short8v Bl1 = *(const short8v*)&Xl[fraddr(rB + 16, g)];
    const short8v Bh2 = *(const short8v*)&Xh[fraddr(rB + 32, g)];
    const short8v Bl2 = *(const short8v*)&Xl[fraddr(rB + 32, g)];
    const short8v Bh3 = *(const short8v*)&Xh[fraddr(rB + 48, g)];
    const short8v Bl3 = *(const short8v*)&Xl[fraddr(rB + 48, g)];
    acc0 = __builtin_amdgcn_mfma_f32_16x16x32_bf16(Ah, Bh0, acc0, 0, 0, 0);
    acc0 = __builtin_amdgcn_mfma_f32_16x16x32_bf16(Ah, Bl0, acc0, 0, 0, 0);
    acc0 = __builtin_amdgcn_mfma_f32_16x16x32_bf16(Al, Bh0, acc0, 0, 0, 0);
    acc0 = __builtin_amdgcn_mfma_f32_16x16x32_bf16(Al, Bl0, acc0, 0, 0, 0);
    acc1 = __builtin_amdgcn_mfma_f32_16x16x32_bf16(Ah, Bh1, acc1, 0, 0, 0);
    acc1 = __builtin_amdgcn_mfma_f32_16x16x32_bf16(Ah, Bl1, acc1, 0, 0, 0);
    acc1 = __builtin_amdgcn_mfma_f32_16x16x32_bf16(Al, Bh1, acc1, 0, 0, 0);
    acc1 = __builtin_amdgcn_mfma_f32_16x16x32_bf16(Al, Bl1, acc1, 0, 0, 0);
    acc2 = __builtin_amdgcn_mfma_f32_16x16x32_bf16(Ah, Bh2, acc2, 0, 0, 0);
    acc2 = __builtin_amdgcn_mfma_f32_16x16x32_bf16(Ah, Bl2, acc2, 0, 0, 0);
    acc2 = __builtin_amdgcn_mfma_f32_16x16x32_bf16(Al, Bh2, acc2, 0, 0, 0);
    acc2 = __builtin_amdgcn_mfma_f32_16x16x32_bf16(Al, Bl2, acc2, 0, 0, 0);
    acc3 = __builtin_amdgcn_mfma_f32_16x16x32_bf16(Ah, Bh3, acc3, 0, 0, 0);
    acc3 = __builtin_amdgcn_mfma_f32_16x16x32_bf16(Ah, Bl3, acc3, 0, 0, 0);
    acc3 = __builtin_amdgcn_mfma_f32_16x16x32_bf16(Al, Bh3, acc3, 0, 0, 0);
    acc3 = __builtin_amdgcn_mfma_f32_16x16x32_bf16(Al, Bl3, acc3, 0, 0, 0);
  }
  float* Gp = ws + WS_GPART + (size_t)(b*64 + chunk)*4096;
  const int col = lane & 15, rq = lane >> 4;
  #pragma unroll
  for (int r=0;r<4;++r){
    const int row = (w*16 + rq*4 + r)*64;
    Gp[row +  0 + col] = acc0[r];
    Gp[row + 16 + col] = acc1[r];
    Gp[row + 32 + col] = acc2[r];
    Gp[row + 48 + col] = acc3[r];
  }
  sx += __shfl_xor(sx, 1, 4);
  sx += __shfl_xor(sx, 2, 4);
  if (q == 0){
    ws[WS_SXPART + (b*64+chunk)*64 + ch] = sx;
  }
}

// ---------------- KMID: fused middle chain, 256 blocks, 6 phases ----------------
// grid (16 p, 16 b). Phase bodies are the R12-proven kernels.
__global__ __launch_bounds__(256) void kmid(const float* __restrict__ wq,
                                            const float* __restrict__ wk,
                                            const float* __restrict__ wv,
                                            const float* __restrict__ wc,
                                            const float* __restrict__ wl,
                                            const float* __restrict__ g1,
                                            float* __restrict__ ws){
  __shared__ float smem[8836];   // 35.3 KB arena, re-purposed per phase
  const int p = blockIdx.x, b = blockIdx.y;
  const int t = threadIdx.x;

  // ---- Phase 1: coalesced G reduce + Sx reduce + STATS zero ----
  {
    const float* Gp = ws + WS_GPART + (size_t)b*64*4096 + p*256 + t;
    float s = 0.f;
    #pragma unroll 8
    for (int ch=0; ch<64; ++ch) s += Gp[(size_t)ch*4096];
    ws[WS_G + b*4096 + p*256 + t] = s;
    if (p==0 && t<64){
      float sv = 0.f;
      #pragma unroll 8
      for (int ch=0; ch<64; ++ch) sv += ws[WS_SXPART + (b*64+ch)*64 + t];
      ws[WS_SX + b*64 + t] = sv;
    }
    if (p==0 && b==0) ws[WS_STATS + t] = 0.f;
  }
  gridbar(ws, 0);

  // ---- Phase 2: S1T = (wq G)^T (R4/R8-proven ka2; only p<4 work) ----
  if (p < 4){
    float* Gt = smem;   // [64][68]
    const float* G = ws + WS_G + b*4096;
    #pragma unroll
    for (int r=0;r<4;++r){
      const int idx = r*1024 + t*4;
      *(float4*)&Gt[(idx>>6)*68 + (idx&63)] = *(const float4*)(G + idx);
    }
    __syncthreads();
    const int il = t>>2, cq = t&3;
    const int i = p*64 + il;
    const float* wqr = wq + i*64;
    float4 a0={0,0,0,0}, a1={0,0,0,0}, a2={0,0,0,0}, a3={0,0,0,0};
    #pragma unroll 8
    for (int k=0;k<64;++k){
      const float a = wqr[k];
      const float4 g0 = *(const float4*)&Gt[k*68 + cq*16 + 0];
      const float4 g1v = *(const float4*)&Gt[k*68 + cq*16 + 4];
      const float4 g2 = *(const float4*)&Gt[k*68 + cq*16 + 8];
      const float4 g3 = *(const float4*)&Gt[k*68 + cq*16 + 12];
      a0.x=fmaf(a,g0.x,a0.x); a0.y=fmaf(a,g0.y,a0.y); a0.z=fmaf(a,g0.z,a0.z); a0.w=fmaf(a,g0.w,a0.w);
      a1.x=fmaf(a,g1v.x,a1.x); a1.y=fmaf(a,g1v.y,a1.y); a1.z=fmaf(a,g1v.z,a1.z); a1.w=fmaf(a,g1v.w,a1.w);
      a2.x=fmaf(a,g2.x,a2.x); a2.y=fmaf(a,g2.y,a2.y); a2.z=fmaf(a,g2.z,a2.z); a2.w=fmaf(a,g2.w,a2.w);
      a3.x=fmaf(a,g3.x,a3.x); a3.y=fmaf(a,g3.y,a3.y); a3.z=fmaf(a,g3.z,a3.z); a3.w=fmaf(a,g3.w,a3.w);
    }
    float* S1T = ws + WS_S1T + b*16384;
    const int c0 = cq*16;
    S1T[(c0+ 0)*256 + i]=a0.x; S1T[(c0+ 1)*256 + i]=a0.y; S1T[(c0+ 2)*256 + i]=a0.z; S1T[(c0+ 3)*256 + i]=a0.w;
    S1T[(c0+ 4)*256 + i]=a1.x; S1T[(c0+ 5)*256 + i]=a1.y; S1T[(c0+ 6)*256 + i]=a1.z; S1T[(c0+ 7)*256 + i]=a1.w;
    S1T[(c0+ 8)*256 + i]=a2.x; S1T[(c0+ 9)*256 + i]=a2.y; S1T[(c0+10)*256 + i]=a2.z; S1T[(c0+11)*256 + i]=a2.w;
    S1T[(c0+12)*256 + i]=a3.x; S1T[(c0+13)*256 + i]=a3.y; S1T[(c0+14)*256 + i]=a3.z; S1T[(c0+15)*256 + i]=a3.w;
  }
  gridbar(ws, 1);

  // ---- Phase 3: scores + column softmax + PV partial (R12 kb12) ----
  {
    float* scl   = smem;          // [256*17]
    float* pstat = smem + 4352;   // [256]
    float* fstat = smem + 4608;   // [32]
    const int jp = p, j0 = jp*16;
    const float* S1Tb = ws + WS_S1T + b*16384;
    float sc[16];
    #pragma unroll
    for (int jj=0;jj<16;++jj) sc[jj]=0.f;
    #pragma unroll 2
    for (int k=0;k<64;++k){
      const float s1 = S1Tb[k*256 + t];
      const float* wkr = wk + j0*64 + k;
      #pragma unroll
      for (int jj=0;jj<16;++jj)
        sc[jj] = fmaf(wkr[jj*64], s1, sc[jj]);
    }
    #pragma unroll
    for (int jj=0;jj<16;++jj) scl[t*17+jj] = sc[jj];
    __syncthreads();
    const int col = t&15, ig = t>>4;
    {
      float m = -3.0e38f;
      #pragma unroll
      for (int q=0;q<16;++q) m = fmaxf(m, scl[(ig*16+q)*17 + col]);
      pstat[ig*16+col] = m;
    }
    __syncthreads();
    if (t<16){
      float m = -3.0e38f;
      #pragma unroll
      for (int q=0;q<16;++q) m = fmaxf(m, pstat[q*16+t]);
      fstat[t] = m;
    }
    __syncthreads();
    {
      const float mj = fstat[col];
      float s = 0.f;
      #pragma unroll
      for (int q=0;q<16;++q) s += __expf(scl[(ig*16+q)*17 + col] - mj);
      pstat[ig*16+col] = s;
    }
    __syncthreads();
    if (t<16){
      float s = 0.f;
      #pragma unroll
      for (int q=0;q<16;++q) s += pstat[q*16+t];
      fstat[16+t] = 1.f/s;
    }
    __syncthreads();
    #pragma unroll
    for (int jj=0;jj<16;++jj)
      sc[jj] = __expf(sc[jj] - fstat[jj]) * fstat[16+jj];
    float* Vp = ws + WS_V1P + (size_t)(b*16 + jp)*16384;
    for (int cb=0; cb<4; ++cb){
      float acc[16];
      #pragma unroll
      for (int cc=0;cc<16;++cc) acc[cc]=0.f;
      #pragma unroll
      for (int jj=0;jj<16;++jj){
        const float pv = sc[jj];
        const float* wvr = wv + (j0+jj)*64 + cb*16;  // uniform -> s_load
        #pragma unroll
        for (int cc=0;cc<16;++cc)
          acc[cc] = fmaf(pv, wvr[cc], acc[cc]);
      }
      #pragma unroll
      for (int cc=0;cc<16;++cc)
        Vp[(cb*16+cc)*256 + t] = acc[cc];
    }
  }
  gridbar(ws, 2);

  // ---- Phase 4: V1 partial-sum + M K-partials (R12 kc v2) ----
  {
    float* V1l = smem;   // [16][65]
    const int kq = p;
    #pragma unroll
    for (int r=0;r<4;++r){
      const int e = t + 256*r;
      const int il = e & 15, c = e >> 4;
      const float* Vp = ws + WS_V1P + (size_t)b*16*16384 + c*256 + kq*16 + il;
      float s = 0.f;
      #pragma unroll
      for (int jp2=0;jp2<16;++jp2) s += Vp[jp2*16384];
      V1l[il*65 + c] = s * INV_SQRT_H;
    }
    __syncthreads();
    const int c = t & 63;
    const int og = __builtin_amdgcn_readfirstlane(t >> 6);
    float acc[16];
    #pragma unroll
    for (int oo=0;oo<16;++oo) acc[oo]=0.f;
    #pragma unroll
    for (int il=0; il<16; ++il){
      const float v = V1l[il*65 + c];
      const float* wcr = wc + (og*16)*256 + kq*16 + il;  // uniform -> s_load
      #pragma unroll
      for (int oo=0;oo<16;++oo)
        acc[oo] = fmaf(wcr[oo*256], v, acc[oo]);
    }
    float* Mp = ws + WS_MPART + (size_t)(b*16 + kq)*4096;
    #pragma unroll
    for (int oo=0;oo<16;++oo)
      Mp[(og*16+oo)*64 + c] = acc[oo];
  }
  gridbar(ws, 3);

  // ---- Phase 5: M rows + BN1 stats (R12 kd v2) ----
  {
    float* Msub = smem;          // [4][65]
    float* Gl   = smem + 260;    // [64][67]
    float* Sxl  = smem + 4548;   // [64]
    const int oq = p;
    const int o = t >> 6, lane = t & 63;
    const int row = oq*4 + o;
    {
      const float* Mp = ws + WS_MPART + (size_t)b*16*4096 + row*64 + lane;
      float s = 0.f;
      #pragma unroll
      for (int kq=0;kq<16;++kq) s += Mp[kq*4096];
      ws[WS_M + b*4096 + row*64 + lane] = s;
      Msub[o*65 + lane] = s;
    }
    #pragma unroll
    for (int r=0;r<16;++r){
      const int e = t + 256*r;
      Gl[(e>>6)*67 + (e&63)] = ws[WS_G + b*4096 + e];
    }
    if (t<64) Sxl[t] = ws[WS_SX + b*64 + t];
    __syncthreads();
    float sk = 0.f;
    #pragma unroll 4
    for (int c=0;c<64;++c) sk = fmaf(Gl[lane*67+c], Msub[o*65+c], sk);
    float d = Msub[o*65 + lane] * sk;
    float s1 = Msub[o*65 + lane] * Sxl[lane];
    #pragma unroll
    for (int off=1; off<64; off<<=1){
      d  += __shfl_xor(d,  off);
      s1 += __shfl_xor(s1, off);
    }
    if (lane==0){
      atomicAdd(&ws[WS_STATS + row], s1);
      atomicAdd(&ws[WS_STATS + 64 + row], d);
    }
  }
  gridbar(ws, 4);

  // ---- Phase 6: N rows + BN2 stats (R12 ke v2) ----
  {
    float* Ml   = smem;           // [64][65]
    float* Gl   = smem + 4160;    // [64][67]
    float* Nsub = smem + 8448;    // [4][65]
    float* Sxl  = smem + 8708;    // [64]
    float* a1l  = smem + 8772;    // [64]
    const int oq = p;
    const int o = t >> 6, lane = t & 63;
    const int row = oq*4 + o;
    if (t<64){
      const float mean1 = ws[WS_STATS+t]*INV_BL;
      const float var1 = ws[WS_STATS+64+t]*INV_BL - mean1*mean1;
      a1l[t] = g1[t]*rsqrtf(var1 + EPSV);
      Sxl[t] = ws[WS_SX + b*64 + t];
    }
    #pragma unroll
    for (int r=0;r<16;++r){
      const int e = t + 256*r;
      Ml[(e>>6)*65 + (e&63)] = ws[WS_M + b*4096 + e];
      Gl[(e>>6)*67 + (e&63)] = ws[WS_G + b*4096 + e];
    }
    __syncthreads();
    float acc = 0.f;
    #pragma unroll 4
    for (int k=0;k<64;++k){
      const float wk_ = wl[row*64 + k] * a1l[k];
      acc = fmaf(wk_, Ml[k*65 + lane], acc);
    }
    const float nv = acc + wl[row*64 + lane];
    ws[WS_N + b*4096 + row*64 + lane] = nv;
    Nsub[o*65 + lane] = nv;
    __syncthreads();
    float sk = 0.f;
    #pragma unroll 4
    for (int c=0;c<64;++c) sk = fmaf(Gl[lane*67+c], Nsub[o*65+c], sk);
    float d = Nsub[o*65 + lane] * sk;
    float s2 = Nsub[o*65 + lane] * Sxl[lane];
    #pragma unroll
    for (int off=1; off<64; off<<=1){
      d  += __shfl_xor(d,  off);
      s2 += __shfl_xor(s2, off);
    }
    if (lane==0){
      atomicAdd(&ws[WS_STATS + 128 + row], s2);
      atomicAdd(&ws[WS_STATS + 192 + row], d);
    }
  }
}

// ---------------- K3: out = relu(a2*(N x) + e) (R12-proven) ----------------
__global__ __launch_bounds__(256) void k3_out(const float* __restrict__ x,
                                              const float* __restrict__ g2,
                                              const float* __restrict__ b2,
                                              const float* __restrict__ ws,
                                              float* __restrict__ out){
  __shared__ float a2l[64], el[64];
  const int b = blockIdx.y, lc = blockIdx.x;
  const int t = threadIdx.x;
  if (t<64){
    const float mu = ws[WS_STATS+128+t]*INV_BL;
    const float var2 = ws[WS_STATS+192+t]*INV_BL - mu*mu;
    const float a2 = g2[t]*rsqrtf(var2 + EPSV);
    a2l[t] = a2;
    el[t] = b2[t] - a2*mu;
  }
  __syncthreads();
  const int w = __builtin_amdgcn_readfirstlane(t >> 6);
  const int lane = t & 63;
  const int l = lc*256 + 4*lane;
  const float* Np = ws + WS_N + b*4096 + w*1024;
  const float* xb = x + b*TC*TL + l;
  float4 acc[16];
  #pragma unroll
  for (int oo=0;oo<16;++oo){ acc[oo].x=0.f; acc[oo].y=0.f; acc[oo].z=0.f; acc[oo].w=0.f; }
  #pragma unroll 4
  for (int c=0;c<64;++c){
    const float4 xv = *(const float4*)(xb + c*TL);
    #pragma unroll
    for (int oo=0;oo<16;++oo){
      const float nv = Np[oo*64 + c];
      acc[oo].x = fmaf(nv, xv.x, acc[oo].x);
      acc[oo].y = fmaf(nv, xv.y, acc[oo].y);
      acc[oo].z = fmaf(nv, xv.z, acc[oo].z);
      acc[oo].w = fmaf(nv, xv.w, acc[oo].w);
    }
  }
  #pragma unroll
  for (int oo=0;oo<16;++oo){
    const float a2v = a2l[w*16+oo], ev = el[w*16+oo];
    float4 r;
    r.x = fmaxf(fmaf(a2v, acc[oo].x, ev), 0.f);
    r.y = fmaxf(fmaf(a2v, acc[oo].y, ev), 0.f);
    r.z = fmaxf(fmaf(a2v, acc[oo].z, ev), 0.f);
    r.w = fmaxf(fmaf(a2v, acc[oo].w, ev), 0.f);
    *(float4*)(out + (b*TC + w*16 + oo)*TL + l) = r;
  }
}

extern "C" void kernel_launch(void* const* d_in, const int* in_sizes, int n_in,
                              void* d_out, int out_size, void* d_ws, size_t ws_size,
                              hipStream_t stream){
  const float* x  = (const float*)d_in[0];
  const float* wk = (const float*)d_in[1];
  const float* wq = (const float*)d_in[2];
  const float* wv = (const float*)d_in[3];
  const float* wc = (const float*)d_in[4];
  const float* g1 = (const float*)d_in[5];
  /* b1 (d_in[6]) provably cancels through BN2 mean-subtraction */
  const float* wl = (const float*)d_in[7];
  const float* g2 = (const float*)d_in[8];
  const float* b2 = (const float*)d_in[9];
  float* out = (float*)d_out;
  float* ws  = (float*)d_ws;

  k1_gram<<<dim3(64,16), 256, 0, stream>>>(x, ws);
  kmid   <<<dim3(16,16), 256, 0, stream>>>(wq, wk, wv, wc, wl, g1, ws);
  k3_out <<<dim3(32,16), 256, 0, stream>>>(x, g2, b2, ws, out);
}

// Round 14
// 121.025 us; speedup vs baseline: 1.6336x; 1.6336x over previous
//
#include <hip/hip_runtime.h>
#include <math.h>

#define TB 16
#define TL 8192
#define TC 64

constexpr float INV_BL = 1.0f / (16.0f * 8192.0f);
constexpr float EPSV = 1e-5f;
constexpr float INV_SQRT_H = 0.17677669529663687f; // 1/sqrt(32)

// workspace offsets (floats) — ws is 256 MiB
#define WS_G      0        /* [16][64][64] */
#define WS_SX     65536    /* [16][64] */
#define WS_STATS  66560    /* s1[64] d1[64] s2[64] d2[64] */
#define WS_M      66816    /* [16][64][64] */
#define WS_N      132352   /* [16][64][64] */
#define WS_S1T    197888   /* [16][64][256] -> ends 460032 */
#define WS_V1P    460032   /* [16][16jp][64c][256i] -> ends 4654336 */
#define WS_GPART  4654336  /* [16][64][4096] -> ends 8848640 */
#define WS_SXPART 8848640  /* [16][64][64] -> ends 8914176 */
#define WS_MPART  8914176  /* [16][16][4096] -> ends 9962752 */

typedef __attribute__((ext_vector_type(8))) short short8v;  // 8 bf16 (4 VGPRs)
typedef __attribute__((ext_vector_type(4))) float f32x4;    // MFMA C/D

__device__ __forceinline__ ushort bf16rne(float f){
  uint u = __float_as_uint(f);
  u += 0x7FFF + ((u >> 16) & 1);
  return (ushort)(u >> 16);
}

__device__ __forceinline__ int fraddr(int ch, int g){
  return ch*128 + 8*(g ^ (ch & 7));
}

// ---------------- K1 v7: single-shot MFMA Gram, 1024 blocks (R12-proven) ----------------
__global__ __launch_bounds__(256) void k1_gram(const float* __restrict__ x,
                                               float* __restrict__ ws){
  __shared__ ushort Xh[64*128];
  __shared__ ushort Xl[64*128];
  const int b = blockIdx.y, chunk = blockIdx.x;
  const int t = threadIdx.x;
  const int lane = t & 63;
  const int w = __builtin_amdgcn_readfirstlane(t >> 6);  // wave 0..3
  const float* xb = x + (size_t)b*TC*TL + (size_t)chunk*128;
  const int ch = t >> 2, q = t & 3;
  float sx = 0.f;
  #pragma unroll
  for (int gg=0; gg<4; ++gg){
    const float4 v0 = *(const float4*)(xb + ch*TL + q*32 + 8*gg);
    const float4 v1 = *(const float4*)(xb + ch*TL + q*32 + 8*gg + 4);
    const float ff[8] = {v0.x,v0.y,v0.z,v0.w,v1.x,v1.y,v1.z,v1.w};
    union { short8v v; ushort u[8]; } hh, ll;
    #pragma unroll
    for (int i=0;i<8;++i){
      sx += ff[i];
      const ushort hv = bf16rne(ff[i]);
      hh.u[i] = hv;
      ll.u[i] = bf16rne(ff[i] - __uint_as_float(((uint)hv)<<16));
    }
    const int g = q*4 + gg;
    const int wa = ch*128 + 8*(g ^ (ch & 7));
    *(short8v*)&Xh[wa] = hh.v;
    *(short8v*)&Xl[wa] = ll.v;
  }
  __syncthreads();
  const int rA = w*16 + (lane & 15);
  const int gq = lane >> 4;
  f32x4 acc0={0.f,0.f,0.f,0.f}, acc1={0.f,0.f,0.f,0.f},
        acc2={0.f,0.f,0.f,0.f}, acc3={0.f,0.f,0.f,0.f};
  #pragma unroll
  for (int kk=0; kk<4; ++kk){
    const int g = kk*4 + gq;
    const short8v Ah = *(const short8v*)&Xh[fraddr(rA, g)];
    const short8v Al = *(const short8v*)&Xl[fraddr(rA, g)];
    const int rB = (lane & 15);
    const short8v Bh0 = *(const short8v*)&Xh[fraddr(rB,      g)];
    const short8v Bl0 = *(const short8v*)&Xl[fraddr(rB,      g)];
    const short8v Bh1 = *(const short8v*)&Xh[fraddr(rB + 16, g)];
    const short8v Bl1 = *(const short8v*)&Xl[fraddr(rB + 16, g)];
    const short8v Bh2 = *(const short8v*)&Xh[fraddr(rB + 32, g)];
    const short8v Bl2 = *(const short8v*)&Xl[fraddr(rB + 32, g)];
    const short8v Bh3 = *(const short8v*)&Xh[fraddr(rB + 48, g)];
    const short8v Bl3 = *(const short8v*)&Xl[fraddr(rB + 48, g)];
    acc0 = __builtin_amdgcn_mfma_f32_16x16x32_bf16(Ah, Bh0, acc0, 0, 0, 0);
    acc0 = __builtin_amdgcn_mfma_f32_16x16x32_bf16(Ah, Bl0, acc0, 0, 0, 0);
    acc0 = __builtin_amdgcn_mfma_f32_16x16x32_bf16(Al, Bh0, acc0, 0, 0, 0);
    acc0 = __builtin_amdgcn_mfma_f32_16x16x32_bf16(Al, Bl0, acc0, 0, 0, 0);
    acc1 = __builtin_amdgcn_mfma_f32_16x16x32_bf16(Ah, Bh1, acc1, 0, 0, 0);
    acc1 = __builtin_amdgcn_mfma_f32_16x16x32_bf16(Ah, Bl1, acc1, 0, 0, 0);
    acc1 = __builtin_amdgcn_mfma_f32_16x16x32_bf16(Al, Bh1, acc1, 0, 0, 0);
    acc1 = __builtin_amdgcn_mfma_f32_16x16x32_bf16(Al, Bl1, acc1, 0, 0, 0);
    acc2 = __builtin_amdgcn_mfma_f32_16x16x32_bf16(Ah, Bh2, acc2, 0, 0, 0);
    acc2 = __builtin_amdgcn_mfma_f32_16x16x32_bf16(Ah, Bl2, acc2, 0, 0, 0);
    acc2 = __builtin_amdgcn_mfma_f32_16x16x32_bf16(Al, Bh2, acc2, 0, 0, 0);
    acc2 = __builtin_amdgcn_mfma_f32_16x16x32_bf16(Al, Bl2, acc2, 0, 0, 0);
    acc3 = __builtin_amdgcn_mfma_f32_16x16x32_bf16(Ah, Bh3, acc3, 0, 0, 0);
    acc3 = __builtin_amdgcn_mfma_f32_16x16x32_bf16(Ah, Bl3, acc3, 0, 0, 0);
    acc3 = __builtin_amdgcn_mfma_f32_16x16x32_bf16(Al, Bh3, acc3, 0, 0, 0);
    acc3 = __builtin_amdgcn_mfma_f32_16x16x32_bf16(Al, Bl3, acc3, 0, 0, 0);
  }
  float* Gp = ws + WS_GPART + (size_t)(b*64 + chunk)*4096;
  const int col = lane & 15, rq = lane >> 4;
  #pragma unroll
  for (int r=0;r<4;++r){
    const int row = (w*16 + rq*4 + r)*64;
    Gp[row +  0 + col] = acc0[r];
    Gp[row + 16 + col] = acc1[r];
    Gp[row + 32 + col] = acc2[r];
    Gp[row + 48 + col] = acc3[r];
  }
  sx += __shfl_xor(sx, 1, 4);
  sx += __shfl_xor(sx, 2, 4);
  if (q == 0){
    ws[WS_SXPART + (b*64+chunk)*64 + ch] = sx;
  }
}

// ---------------- KA1: coalesced G/Sx reduce + STATS zero (R13 phase-1, proven) ----------------
__global__ __launch_bounds__(256) void kA1(float* __restrict__ ws){
  const int p = blockIdx.x, b = blockIdx.y;
  const int t = threadIdx.x;
  const float* Gp = ws + WS_GPART + (size_t)b*64*4096 + p*256 + t;
  float s = 0.f;
  #pragma unroll 8
  for (int ch=0; ch<64; ++ch) s += Gp[(size_t)ch*4096];
  ws[WS_G + b*4096 + p*256 + t] = s;
  if (p==0 && t<64){
    float sv = 0.f;
    #pragma unroll 8
    for (int ch=0; ch<64; ++ch) sv += ws[WS_SXPART + (b*64+ch)*64 + t];
    ws[WS_SX + b*64 + t] = sv;
  }
  if (p==0 && b==0) ws[WS_STATS + t] = 0.f;
}

// ---------------- KA2: S1^T = (wq G)^T (R8-proven ka2) ----------------
__global__ __launch_bounds__(256) void kA2(const float* __restrict__ wq,
                                           float* __restrict__ ws){
  __shared__ float Gt[64*68];
  const int b = blockIdx.y, iblk = blockIdx.x;
  const int t = threadIdx.x;
  const float* G = ws + WS_G + b*4096;
  #pragma unroll
  for (int r=0;r<4;++r){
    const int idx = r*1024 + t*4;
    *(float4*)&Gt[(idx>>6)*68 + (idx&63)] = *(const float4*)(G + idx);
  }
  __syncthreads();
  const int il = t>>2, cq = t&3;
  const int i = iblk*64 + il;
  const float* wqr = wq + i*64;
  float4 a0={0,0,0,0}, a1={0,0,0,0}, a2={0,0,0,0}, a3={0,0,0,0};
  #pragma unroll 8
  for (int k=0;k<64;++k){
    const float a = wqr[k];
    const float4 g0 = *(const float4*)&Gt[k*68 + cq*16 + 0];
    const float4 g1 = *(const float4*)&Gt[k*68 + cq*16 + 4];
    const float4 g2 = *(const float4*)&Gt[k*68 + cq*16 + 8];
    const float4 g3 = *(const float4*)&Gt[k*68 + cq*16 + 12];
    a0.x=fmaf(a,g0.x,a0.x); a0.y=fmaf(a,g0.y,a0.y); a0.z=fmaf(a,g0.z,a0.z); a0.w=fmaf(a,g0.w,a0.w);
    a1.x=fmaf(a,g1.x,a1.x); a1.y=fmaf(a,g1.y,a1.y); a1.z=fmaf(a,g1.z,a1.z); a1.w=fmaf(a,g1.w,a1.w);
    a2.x=fmaf(a,g2.x,a2.x); a2.y=fmaf(a,g2.y,a2.y); a2.z=fmaf(a,g2.z,a2.z); a2.w=fmaf(a,g2.w,a2.w);
    a3.x=fmaf(a,g3.x,a3.x); a3.y=fmaf(a,g3.y,a3.y); a3.z=fmaf(a,g3.z,a3.z); a3.w=fmaf(a,g3.w,a3.w);
  }
  float* S1T = ws + WS_S1T + b*16384;
  const int c0 = cq*16;
  S1T[(c0+ 0)*256 + i]=a0.x; S1T[(c0+ 1)*256 + i]=a0.y; S1T[(c0+ 2)*256 + i]=a0.z; S1T[(c0+ 3)*256 + i]=a0.w;
  S1T[(c0+ 4)*256 + i]=a1.x; S1T[(c0+ 5)*256 + i]=a1.y; S1T[(c0+ 6)*256 + i]=a1.z; S1T[(c0+ 7)*256 + i]=a1.w;
  S1T[(c0+ 8)*256 + i]=a2.x; S1T[(c0+ 9)*256 + i]=a2.y; S1T[(c0+10)*256 + i]=a2.z; S1T[(c0+11)*256 + i]=a2.w;
  S1T[(c0+12)*256 + i]=a3.x; S1T[(c0+13)*256 + i]=a3.y; S1T[(c0+14)*256 + i]=a3.z; S1T[(c0+15)*256 + i]=a3.w;
}

// ---------------- KB12: scores + column softmax + PV partial (R12-proven) ----------------
__global__ __launch_bounds__(256) void kb12(const float* __restrict__ wk,
                                            const float* __restrict__ wv,
                                            float* __restrict__ ws){
  __shared__ float scl[256*17];
  __shared__ float pstat[256];
  __shared__ float fstat[32];
  const int b = blockIdx.y, jp = blockIdx.x;
  const int j0 = jp*16;
  const int t = threadIdx.x;
  const float* S1Tb = ws + WS_S1T + b*16384;
  float sc[16];
  #pragma unroll
  for (int jj=0;jj<16;++jj) sc[jj]=0.f;
  #pragma unroll 2
  for (int k=0;k<64;++k){
    const float s1 = S1Tb[k*256 + t];
    const float* wkr = wk + j0*64 + k;
    #pragma unroll
    for (int jj=0;jj<16;++jj)
      sc[jj] = fmaf(wkr[jj*64], s1, sc[jj]);
  }
  #pragma unroll
  for (int jj=0;jj<16;++jj) scl[t*17+jj] = sc[jj];
  __syncthreads();
  const int col = t&15, ig = t>>4;
  {
    float m = -3.0e38f;
    #pragma unroll
    for (int q=0;q<16;++q) m = fmaxf(m, scl[(ig*16+q)*17 + col]);
    pstat[ig*16+col] = m;
  }
  __syncthreads();
  if (t<16){
    float m = -3.0e38f;
    #pragma unroll
    for (int q=0;q<16;++q) m = fmaxf(m, pstat[q*16+t]);
    fstat[t] = m;
  }
  __syncthreads();
  {
    const float mj = fstat[col];
    float s = 0.f;
    #pragma unroll
    for (int q=0;q<16;++q) s += __expf(scl[(ig*16+q)*17 + col] - mj);
    pstat[ig*16+col] = s;
  }
  __syncthreads();
  if (t<16){
    float s = 0.f;
    #pragma unroll
    for (int q=0;q<16;++q) s += pstat[q*16+t];
    fstat[16+t] = 1.f/s;
  }
  __syncthreads();
  #pragma unroll
  for (int jj=0;jj<16;++jj)
    sc[jj] = __expf(sc[jj] - fstat[jj]) * fstat[16+jj];
  float* Vp = ws + WS_V1P + (size_t)(b*16 + jp)*16384;
  for (int cb=0; cb<4; ++cb){
    float acc[16];
    #pragma unroll
    for (int cc=0;cc<16;++cc) acc[cc]=0.f;
    #pragma unroll
    for (int jj=0;jj<16;++jj){
      const float p = sc[jj];
      const float* wvr = wv + (j0+jj)*64 + cb*16;  // uniform -> s_load
      #pragma unroll
      for (int cc=0;cc<16;++cc)
        acc[cc] = fmaf(p, wvr[cc], acc[cc]);
    }
    #pragma unroll
    for (int cc=0;cc<16;++cc)
      Vp[(cb*16+cc)*256 + t] = acc[cc];       // [c][row], coalesced
  }
}

// ---------------- KC v2: sum V1 partials (16-row slice) + M K-partials (R12-proven) ----------------
__global__ __launch_bounds__(256) void kc_mpart(const float* __restrict__ wc,
                                                float* __restrict__ ws){
  __shared__ float V1l[16*65];
  const int b = blockIdx.y, kq = blockIdx.x;
  const int t = threadIdx.x;
  #pragma unroll
  for (int r=0;r<4;++r){
    const int e = t + 256*r;
    const int il = e & 15, c = e >> 4;
    const float* Vp = ws + WS_V1P + (size_t)b*16*16384 + c*256 + kq*16 + il;
    float s = 0.f;
    #pragma unroll
    for (int jp=0;jp<16;++jp) s += Vp[jp*16384];
    V1l[il*65 + c] = s * INV_SQRT_H;
  }
  __syncthreads();
  const int c = t & 63;
  const int og = __builtin_amdgcn_readfirstlane(t >> 6);
  float acc[16];
  #pragma unroll
  for (int oo=0;oo<16;++oo) acc[oo]=0.f;
  #pragma unroll
  for (int il=0; il<16; ++il){
    const float v = V1l[il*65 + c];
    const float* wcr = wc + (og*16)*256 + kq*16 + il;  // uniform -> s_load
    #pragma unroll
    for (int oo=0;oo<16;++oo)
      acc[oo] = fmaf(wcr[oo*256], v, acc[oo]);
  }
  float* Mp = ws + WS_MPART + (size_t)(b*16 + kq)*4096;
  #pragma unroll
  for (int oo=0;oo<16;++oo)
    Mp[(og*16+oo)*64 + c] = acc[oo];
}

// ---------------- KD v2: M rows + BN1 stats (R12-proven) ----------------
__global__ __launch_bounds__(256) void kd_stats1(float* __restrict__ ws){
  __shared__ float Msub[4*65];
  __shared__ float Gl[64*67];
  __shared__ float Sxl[64];
  const int b = blockIdx.y, oq = blockIdx.x;
  const int t = threadIdx.x;
  const int o = t >> 6, lane = t & 63;
  const int row = oq*4 + o;
  {
    const float* Mp = ws + WS_MPART + (size_t)b*16*4096 + row*64 + lane;
    float s = 0.f;
    #pragma unroll
    for (int kq=0;kq<16;++kq) s += Mp[kq*4096];
    ws[WS_M + b*4096 + row*64 + lane] = s;
    Msub[o*65 + lane] = s;
  }
  #pragma unroll
  for (int r=0;r<16;++r){
    const int e = t + 256*r;
    Gl[(e>>6)*67 + (e&63)] = ws[WS_G + b*4096 + e];
  }
  if (t<64) Sxl[t] = ws[WS_SX + b*64 + t];
  __syncthreads();
  float sk = 0.f;
  #pragma unroll 4
  for (int c=0;c<64;++c) sk = fmaf(Gl[lane*67+c], Msub[o*65+c], sk);
  float d = Msub[o*65 + lane] * sk;
  float s1 = Msub[o*65 + lane] * Sxl[lane];
  #pragma unroll
  for (int off=1; off<64; off<<=1){
    d  += __shfl_xor(d,  off);
    s1 += __shfl_xor(s1, off);
  }
  if (lane==0){
    atomicAdd(&ws[WS_STATS + row], s1);
    atomicAdd(&ws[WS_STATS + 64 + row], d);
  }
}

// ---------------- KE v2: N rows + BN2 stats (R12-proven) ----------------
__global__ __launch_bounds__(256) void ke_n_stats2(const float* __restrict__ wl,
                                                   const float* __restrict__ g1,
                                                   float* __restrict__ ws){
  __shared__ float Ml[64*65];
  __shared__ float Gl[64*67];
  __shared__ float Nsub[4*65];
  __shared__ float Sxl[64], a1l[64];
  const int b = blockIdx.y, oq = blockIdx.x;
  const int t = threadIdx.x;
  const int o = t >> 6, lane = t & 63;
  const int row = oq*4 + o;
  if (t<64){
    const float mean1 = ws[WS_STATS+t]*INV_BL;
    const float var1 = ws[WS_STATS+64+t]*INV_BL - mean1*mean1;
    a1l[t] = g1[t]*rsqrtf(var1 + EPSV);
    Sxl[t] = ws[WS_SX + b*64 + t];
  }
  #pragma unroll
  for (int r=0;r<16;++r){
    const int e = t + 256*r;
    Ml[(e>>6)*65 + (e&63)] = ws[WS_M + b*4096 + e];
    Gl[(e>>6)*67 + (e&63)] = ws[WS_G + b*4096 + e];
  }
  __syncthreads();
  float acc = 0.f;
  #pragma unroll 4
  for (int k=0;k<64;++k){
    const float wk_ = wl[row*64 + k] * a1l[k];
    acc = fmaf(wk_, Ml[k*65 + lane], acc);
  }
  const float nv = acc + wl[row*64 + lane];
  ws[WS_N + b*4096 + row*64 + lane] = nv;
  Nsub[o*65 + lane] = nv;
  __syncthreads();
  float sk = 0.f;
  #pragma unroll 4
  for (int c=0;c<64;++c) sk = fmaf(Gl[lane*67+c], Nsub[o*65+c], sk);
  float d = Nsub[o*65 + lane] * sk;
  float s2 = Nsub[o*65 + lane] * Sxl[lane];
  #pragma unroll
  for (int off=1; off<64; off<<=1){
    d  += __shfl_xor(d,  off);
    s2 += __shfl_xor(s2, off);
  }
  if (lane==0){
    atomicAdd(&ws[WS_STATS + 128 + row], s2);
    atomicAdd(&ws[WS_STATS + 192 + row], d);
  }
}

// ---------------- K3 v2: LDS-staged x (dbuf) + s_load N ----------------
// grid (32 lc, 16 b), 256 threads. x window [64ch][256l] staged in 16-ch chunks.
__global__ __launch_bounds__(256) void k3_out(const float* __restrict__ x,
                                              const float* __restrict__ g2,
                                              const float* __restrict__ b2,
                                              const float* __restrict__ ws,
                                              float* __restrict__ out){
  __shared__ float xl[2][4096];   // 2 x (16 ch x 256 l) = 32 KB
  __shared__ float a2l[64], el[64];
  const int b = blockIdx.y, lc = blockIdx.x;
  const int t = threadIdx.x;
  if (t<64){
    const float mu = ws[WS_STATS+128+t]*INV_BL;
    const float var2 = ws[WS_STATS+192+t]*INV_BL - mu*mu;
    const float a2 = g2[t]*rsqrtf(var2 + EPSV);
    a2l[t] = a2;
    el[t] = b2[t] - a2*mu;
  }
  const int w = __builtin_amdgcn_readfirstlane(t >> 6);
  const int lane = t & 63;
  const int chs = t >> 6;            // staging channel sub-index 0..3
  const int pos4 = (t & 63) * 4;     // staging position (bytes/4)
  const float* xb = x + (size_t)b*TC*TL + lc*256;
  const float* Np = ws + WS_N + b*4096 + w*1024;
  float4 rg[4];
  // prologue: stage chunk 0
  #pragma unroll
  for (int r=0;r<4;++r)
    rg[r] = *(const float4*)(xb + (size_t)(chs + 4*r)*TL + pos4);
  #pragma unroll
  for (int r=0;r<4;++r)
    *(float4*)&xl[0][(chs + 4*r)*256 + pos4] = rg[r];
  __syncthreads();
  float4 acc[16];
  #pragma unroll
  for (int oo=0;oo<16;++oo){ acc[oo].x=0.f; acc[oo].y=0.f; acc[oo].z=0.f; acc[oo].w=0.f; }
  for (int cc=0; cc<4; ++cc){
    if (cc<3){
      #pragma unroll
      for (int r=0;r<4;++r)
        rg[r] = *(const float4*)(xb + (size_t)((cc+1)*16 + chs + 4*r)*TL + pos4);
    }
    const float* xc = &xl[cc&1][0];
    #pragma unroll
    for (int c=0;c<16;++c){
      const float4 xv = *(const float4*)&xc[c*256 + 4*lane];
      #pragma unroll
      for (int oo=0;oo<16;++oo){
        const float nv = Np[oo*64 + cc*16 + c];   // uniform -> s_load (scalar-cached)
        acc[oo].x = fmaf(nv, xv.x, acc[oo].x);
        acc[oo].y = fmaf(nv, xv.y, acc[oo].y);
        acc[oo].z = fmaf(nv, xv.z, acc[oo].z);
        acc[oo].w = fmaf(nv, xv.w, acc[oo].w);
      }
    }
    if (cc<3){
      __syncthreads();
      #pragma unroll
      for (int r=0;r<4;++r)
        *(float4*)&xl[(cc+1)&1][(chs + 4*r)*256 + pos4] = rg[r];
      __syncthreads();
    }
  }
  const int l = lc*256 + 4*lane;
  #pragma unroll
  for (int oo=0;oo<16;++oo){
    const float a2v = a2l[w*16+oo], ev = el[w*16+oo];
    float4 r;
    r.x = fmaxf(fmaf(a2v, acc[oo].x, ev), 0.f);
    r.y = fmaxf(fmaf(a2v, acc[oo].y, ev), 0.f);
    r.z = fmaxf(fmaf(a2v, acc[oo].z, ev), 0.f);
    r.w = fmaxf(fmaf(a2v, acc[oo].w, ev), 0.f);
    *(float4*)(out + (size_t)(b*TC + w*16 + oo)*TL + l) = r;
  }
}

extern "C" void kernel_launch(void* const* d_in, const int* in_sizes, int n_in,
                              void* d_out, int out_size, void* d_ws, size_t ws_size,
                              hipStream_t stream){
  const float* x  = (const float*)d_in[0];
  const float* wk = (const float*)d_in[1];
  const float* wq = (const float*)d_in[2];
  const float* wv = (const float*)d_in[3];
  const float* wc = (const float*)d_in[4];
  const float* g1 = (const float*)d_in[5];
  /* b1 (d_in[6]) provably cancels through BN2 mean-subtraction */
  const float* wl = (const float*)d_in[7];
  const float* g2 = (const float*)d_in[8];
  const float* b2 = (const float*)d_in[9];
  float* out = (float*)d_out;
  float* ws  = (float*)d_ws;

  k1_gram    <<<dim3(64,16), 256, 0, stream>>>(x, ws);
  kA1        <<<dim3(16,16), 256, 0, stream>>>(ws);
  kA2        <<<dim3(4,16),  256, 0, stream>>>(wq, ws);
  kb12       <<<dim3(16,16), 256, 0, stream>>>(wk, wv, ws);
  kc_mpart   <<<dim3(16,16), 256, 0, stream>>>(wc, ws);
  kd_stats1  <<<dim3(16,16), 256, 0, stream>>>(ws);
  ke_n_stats2<<<dim3(16,16), 256, 0, stream>>>(wl, g1, ws);
  k3_out     <<<dim3(32,16), 256, 0, stream>>>(x, g2, b2, ws, out);
}

// Round 15
// 101.090 us; speedup vs baseline: 1.9558x; 1.1972x over previous
//
#include <hip/hip_runtime.h>
#include <math.h>

#define TB 16
#define TL 8192
#define TC 64

constexpr float INV_BL = 1.0f / (16.0f * 8192.0f);
constexpr float EPSV = 1e-5f;
constexpr float INV_SQRT_H = 0.17677669529663687f; // 1/sqrt(32)

// workspace offsets (floats) — ws is 256 MiB
#define WS_G      0        /* [16][64][64] */
#define WS_SX     65536    /* [16][64] */
#define WS_STATS  66560    /* s1[64] d1[64] s2[64] d2[64] */
#define WS_M      66816    /* [16][64][64] */
#define WS_N      132352   /* [16][64][64] */
#define WS_S1T    197888   /* [16][64][256] -> ends 460032 */
#define WS_V1P    460032   /* [16][16jp][64c][256i] -> ends 4654336 */
#define WS_GPART  4654336  /* [16][64][4096] -> ends 8848640 */
#define WS_SXPART 8848640  /* [16][64][64] -> ends 8914176 */
#define WS_MPART  8914176  /* [16][16][4096] -> ends 9962752 */

typedef __attribute__((ext_vector_type(8))) short short8v;  // 8 bf16 (4 VGPRs)
typedef __attribute__((ext_vector_type(4))) float f32x4;    // MFMA C/D

__device__ __forceinline__ ushort bf16rne(float f){
  uint u = __float_as_uint(f);
  u += 0x7FFF + ((u >> 16) & 1);
  return (ushort)(u >> 16);
}

__device__ __forceinline__ int fraddr(int ch, int g){
  return ch*128 + 8*(g ^ (ch & 7));
}

// ---------------- K1 v7: single-shot MFMA Gram, 1024 blocks (R12-proven) ----------------
__global__ __launch_bounds__(256) void k1_gram(const float* __restrict__ x,
                                               float* __restrict__ ws){
  __shared__ ushort Xh[64*128];
  __shared__ ushort Xl[64*128];
  const int b = blockIdx.y, chunk = blockIdx.x;
  const int t = threadIdx.x;
  const int lane = t & 63;
  const int w = __builtin_amdgcn_readfirstlane(t >> 6);  // wave 0..3
  const float* xb = x + (size_t)b*TC*TL + (size_t)chunk*128;
  const int ch = t >> 2, q = t & 3;
  float sx = 0.f;
  #pragma unroll
  for (int gg=0; gg<4; ++gg){
    const float4 v0 = *(const float4*)(xb + ch*TL + q*32 + 8*gg);
    const float4 v1 = *(const float4*)(xb + ch*TL + q*32 + 8*gg + 4);
    const float ff[8] = {v0.x,v0.y,v0.z,v0.w,v1.x,v1.y,v1.z,v1.w};
    union { short8v v; ushort u[8]; } hh, ll;
    #pragma unroll
    for (int i=0;i<8;++i){
      sx += ff[i];
      const ushort hv = bf16rne(ff[i]);
      hh.u[i] = hv;
      ll.u[i] = bf16rne(ff[i] - __uint_as_float(((uint)hv)<<16));
    }
    const int g = q*4 + gg;
    const int wa = ch*128 + 8*(g ^ (ch & 7));
    *(short8v*)&Xh[wa] = hh.v;
    *(short8v*)&Xl[wa] = ll.v;
  }
  __syncthreads();
  const int rA = w*16 + (lane & 15);
  const int gq = lane >> 4;
  f32x4 acc0={0.f,0.f,0.f,0.f}, acc1={0.f,0.f,0.f,0.f},
        acc2={0.f,0.f,0.f,0.f}, acc3={0.f,0.f,0.f,0.f};
  #pragma unroll
  for (int kk=0; kk<4; ++kk){
    const int g = kk*4 + gq;
    const short8v Ah = *(const short8v*)&Xh[fraddr(rA, g)];
    const short8v Al = *(const short8v*)&Xl[fraddr(rA, g)];
    const int rB = (lane & 15);
    const short8v Bh0 = *(const short8v*)&Xh[fraddr(rB,      g)];
    const short8v Bl0 = *(const short8v*)&Xl[fraddr(rB,      g)];
    const short8v Bh1 = *(const short8v*)&Xh[fraddr(rB + 16, g)];
    const short8v Bl1 = *(const short8v*)&Xl[fraddr(rB + 16, g)];
    const short8v Bh2 = *(const short8v*)&Xh[fraddr(rB + 32, g)];
    const short8v Bl2 = *(const short8v*)&Xl[fraddr(rB + 32, g)];
    const short8v Bh3 = *(const short8v*)&Xh[fraddr(rB + 48, g)];
    const short8v Bl3 = *(const short8v*)&Xl[fraddr(rB + 48, g)];
    acc0 = __builtin_amdgcn_mfma_f32_16x16x32_bf16(Ah, Bh0, acc0, 0, 0, 0);
    acc0 = __builtin_amdgcn_mfma_f32_16x16x32_bf16(Ah, Bl0, acc0, 0, 0, 0);
    acc0 = __builtin_amdgcn_mfma_f32_16x16x32_bf16(Al, Bh0, acc0, 0, 0, 0);
    acc0 = __builtin_amdgcn_mfma_f32_16x16x32_bf16(Al, Bl0, acc0, 0, 0, 0);
    acc1 = __builtin_amdgcn_mfma_f32_16x16x32_bf16(Ah, Bh1, acc1, 0, 0, 0);
    acc1 = __builtin_amdgcn_mfma_f32_16x16x32_bf16(Ah, Bl1, acc1, 0, 0, 0);
    acc1 = __builtin_amdgcn_mfma_f32_16x16x32_bf16(Al, Bh1, acc1, 0, 0, 0);
    acc1 = __builtin_amdgcn_mfma_f32_16x16x32_bf16(Al, Bl1, acc1, 0, 0, 0);
    acc2 = __builtin_amdgcn_mfma_f32_16x16x32_bf16(Ah, Bh2, acc2, 0, 0, 0);
    acc2 = __builtin_amdgcn_mfma_f32_16x16x32_bf16(Ah, Bl2, acc2, 0, 0, 0);
    acc2 = __builtin_amdgcn_mfma_f32_16x16x32_bf16(Al, Bh2, acc2, 0, 0, 0);
    acc2 = __builtin_amdgcn_mfma_f32_16x16x32_bf16(Al, Bl2, acc2, 0, 0, 0);
    acc3 = __builtin_amdgcn_mfma_f32_16x16x32_bf16(Ah, Bh3, acc3, 0, 0, 0);
    acc3 = __builtin_amdgcn_mfma_f32_16x16x32_bf16(Ah, Bl3, acc3, 0, 0, 0);
    acc3 = __builtin_amdgcn_mfma_f32_16x16x32_bf16(Al, Bh3, acc3, 0, 0, 0);
    acc3 = __builtin_amdgcn_mfma_f32_16x16x32_bf16(Al, Bl3, acc3, 0, 0, 0);
  }
  float* Gp = ws + WS_GPART + (size_t)(b*64 + chunk)*4096;
  const int col = lane & 15, rq = lane >> 4;
  #pragma unroll
  for (int r=0;r<4;++r){
    const int row = (w*16 + rq*4 + r)*64;
    Gp[row +  0 + col] = acc0[r];
    Gp[row + 16 + col] = acc1[r];
    Gp[row + 32 + col] = acc2[r];
    Gp[row + 48 + col] = acc3[r];
  }
  sx += __shfl_xor(sx, 1, 4);
  sx += __shfl_xor(sx, 2, 4);
  if (q == 0){
    ws[WS_SXPART + (b*64+chunk)*64 + ch] = sx;
  }
}

// ---------------- KA1: coalesced G/Sx reduce + STATS zero ----------------
__global__ __launch_bounds__(256) void kA1(float* __restrict__ ws){
  const int p = blockIdx.x, b = blockIdx.y;
  const int t = threadIdx.x;
  const float* Gp = ws + WS_GPART + (size_t)b*64*4096 + p*256 + t;
  float s = 0.f;
  #pragma unroll 8
  for (int ch=0; ch<64; ++ch) s += Gp[(size_t)ch*4096];
  ws[WS_G + b*4096 + p*256 + t] = s;
  if (p==0 && t<64){
    float sv = 0.f;
    #pragma unroll 8
    for (int ch=0; ch<64; ++ch) sv += ws[WS_SXPART + (b*64+ch)*64 + t];
    ws[WS_SX + b*64 + t] = sv;
  }
  if (p==0 && b==0) ws[WS_STATS + t] = 0.f;
}

// ---------------- KA2: S1^T = (wq G)^T (R8-proven) ----------------
__global__ __launch_bounds__(256) void kA2(const float* __restrict__ wq,
                                           float* __restrict__ ws){
  __shared__ float Gt[64*68];
  const int b = blockIdx.y, iblk = blockIdx.x;
  const int t = threadIdx.x;
  const float* G = ws + WS_G + b*4096;
  #pragma unroll
  for (int r=0;r<4;++r){
    const int idx = r*1024 + t*4;
    *(float4*)&Gt[(idx>>6)*68 + (idx&63)] = *(const float4*)(G + idx);
  }
  __syncthreads();
  const int il = t>>2, cq = t&3;
  const int i = iblk*64 + il;
  const float* wqr = wq + i*64;
  float4 a0={0,0,0,0}, a1={0,0,0,0}, a2={0,0,0,0}, a3={0,0,0,0};
  #pragma unroll 8
  for (int k=0;k<64;++k){
    const float a = wqr[k];
    const float4 g0 = *(const float4*)&Gt[k*68 + cq*16 + 0];
    const float4 g1 = *(const float4*)&Gt[k*68 + cq*16 + 4];
    const float4 g2 = *(const float4*)&Gt[k*68 + cq*16 + 8];
    const float4 g3 = *(const float4*)&Gt[k*68 + cq*16 + 12];
    a0.x=fmaf(a,g0.x,a0.x); a0.y=fmaf(a,g0.y,a0.y); a0.z=fmaf(a,g0.z,a0.z); a0.w=fmaf(a,g0.w,a0.w);
    a1.x=fmaf(a,g1.x,a1.x); a1.y=fmaf(a,g1.y,a1.y); a1.z=fmaf(a,g1.z,a1.z); a1.w=fmaf(a,g1.w,a1.w);
    a2.x=fmaf(a,g2.x,a2.x); a2.y=fmaf(a,g2.y,a2.y); a2.z=fmaf(a,g2.z,a2.z); a2.w=fmaf(a,g2.w,a2.w);
    a3.x=fmaf(a,g3.x,a3.x); a3.y=fmaf(a,g3.y,a3.y); a3.z=fmaf(a,g3.z,a3.z); a3.w=fmaf(a,g3.w,a3.w);
  }
  float* S1T = ws + WS_S1T + b*16384;
  const int c0 = cq*16;
  S1T[(c0+ 0)*256 + i]=a0.x; S1T[(c0+ 1)*256 + i]=a0.y; S1T[(c0+ 2)*256 + i]=a0.z; S1T[(c0+ 3)*256 + i]=a0.w;
  S1T[(c0+ 4)*256 + i]=a1.x; S1T[(c0+ 5)*256 + i]=a1.y; S1T[(c0+ 6)*256 + i]=a1.z; S1T[(c0+ 7)*256 + i]=a1.w;
  S1T[(c0+ 8)*256 + i]=a2.x; S1T[(c0+ 9)*256 + i]=a2.y; S1T[(c0+10)*256 + i]=a2.z; S1T[(c0+11)*256 + i]=a2.w;
  S1T[(c0+12)*256 + i]=a3.x; S1T[(c0+13)*256 + i]=a3.y; S1T[(c0+14)*256 + i]=a3.z; S1T[(c0+15)*256 + i]=a3.w;
}

// ---------------- KB12: scores + column softmax + PV partial (R12-proven) ----------------
__global__ __launch_bounds__(256) void kb12(const float* __restrict__ wk,
                                            const float* __restrict__ wv,
                                            float* __restrict__ ws){
  __shared__ float scl[256*17];
  __shared__ float pstat[256];
  __shared__ float fstat[32];
  const int b = blockIdx.y, jp = blockIdx.x;
  const int j0 = jp*16;
  const int t = threadIdx.x;
  const float* S1Tb = ws + WS_S1T + b*16384;
  float sc[16];
  #pragma unroll
  for (int jj=0;jj<16;++jj) sc[jj]=0.f;
  #pragma unroll 2
  for (int k=0;k<64;++k){
    const float s1 = S1Tb[k*256 + t];
    const float* wkr = wk + j0*64 + k;
    #pragma unroll
    for (int jj=0;jj<16;++jj)
      sc[jj] = fmaf(wkr[jj*64], s1, sc[jj]);
  }
  #pragma unroll
  for (int jj=0;jj<16;++jj) scl[t*17+jj] = sc[jj];
  __syncthreads();
  const int col = t&15, ig = t>>4;
  {
    float m = -3.0e38f;
    #pragma unroll
    for (int q=0;q<16;++q) m = fmaxf(m, scl[(ig*16+q)*17 + col]);
    pstat[ig*16+col] = m;
  }
  __syncthreads();
  if (t<16){
    float m = -3.0e38f;
    #pragma unroll
    for (int q=0;q<16;++q) m = fmaxf(m, pstat[q*16+t]);
    fstat[t] = m;
  }
  __syncthreads();
  {
    const float mj = fstat[col];
    float s = 0.f;
    #pragma unroll
    for (int q=0;q<16;++q) s += __expf(scl[(ig*16+q)*17 + col] - mj);
    pstat[ig*16+col] = s;
  }
  __syncthreads();
  if (t<16){
    float s = 0.f;
    #pragma unroll
    for (int q=0;q<16;++q) s += pstat[q*16+t];
    fstat[16+t] = 1.f/s;
  }
  __syncthreads();
  #pragma unroll
  for (int jj=0;jj<16;++jj)
    sc[jj] = __expf(sc[jj] - fstat[jj]) * fstat[16+jj];
  float* Vp = ws + WS_V1P + (size_t)(b*16 + jp)*16384;
  for (int cb=0; cb<4; ++cb){
    float acc[16];
    #pragma unroll
    for (int cc=0;cc<16;++cc) acc[cc]=0.f;
    #pragma unroll
    for (int jj=0;jj<16;++jj){
      const float p = sc[jj];
      const float* wvr = wv + (j0+jj)*64 + cb*16;  // uniform -> s_load
      #pragma unroll
      for (int cc=0;cc<16;++cc)
        acc[cc] = fmaf(p, wvr[cc], acc[cc]);
    }
    #pragma unroll
    for (int cc=0;cc<16;++cc)
      Vp[(cb*16+cc)*256 + t] = acc[cc];       // [c][row], coalesced
  }
}

// ---------------- KC v2: sum V1 partials + M K-partials (R12-proven) ----------------
__global__ __launch_bounds__(256) void kc_mpart(const float* __restrict__ wc,
                                                float* __restrict__ ws){
  __shared__ float V1l[16*65];
  const int b = blockIdx.y, kq = blockIdx.x;
  const int t = threadIdx.x;
  #pragma unroll
  for (int r=0;r<4;++r){
    const int e = t + 256*r;
    const int il = e & 15, c = e >> 4;
    const float* Vp = ws + WS_V1P + (size_t)b*16*16384 + c*256 + kq*16 + il;
    float s = 0.f;
    #pragma unroll
    for (int jp=0;jp<16;++jp) s += Vp[jp*16384];
    V1l[il*65 + c] = s * INV_SQRT_H;
  }
  __syncthreads();
  const int c = t & 63;
  const int og = __builtin_amdgcn_readfirstlane(t >> 6);
  float acc[16];
  #pragma unroll
  for (int oo=0;oo<16;++oo) acc[oo]=0.f;
  #pragma unroll
  for (int il=0; il<16; ++il){
    const float v = V1l[il*65 + c];
    const float* wcr = wc + (og*16)*256 + kq*16 + il;  // uniform -> s_load
    #pragma unroll
    for (int oo=0;oo<16;++oo)
      acc[oo] = fmaf(wcr[oo*256], v, acc[oo]);
  }
  float* Mp = ws + WS_MPART + (size_t)(b*16 + kq)*4096;
  #pragma unroll
  for (int oo=0;oo<16;++oo)
    Mp[(og*16+oo)*64 + c] = acc[oo];
}

// ---------------- KD v2: M rows + BN1 stats (R12-proven) ----------------
__global__ __launch_bounds__(256) void kd_stats1(float* __restrict__ ws){
  __shared__ float Msub[4*65];
  __shared__ float Gl[64*67];
  __shared__ float Sxl[64];
  const int b = blockIdx.y, oq = blockIdx.x;
  const int t = threadIdx.x;
  const int o = t >> 6, lane = t & 63;
  const int row = oq*4 + o;
  {
    const float* Mp = ws + WS_MPART + (size_t)b*16*4096 + row*64 + lane;
    float s = 0.f;
    #pragma unroll
    for (int kq=0;kq<16;++kq) s += Mp[kq*4096];
    ws[WS_M + b*4096 + row*64 + lane] = s;
    Msub[o*65 + lane] = s;
  }
  #pragma unroll
  for (int r=0;r<16;++r){
    const int e = t + 256*r;
    Gl[(e>>6)*67 + (e&63)] = ws[WS_G + b*4096 + e];
  }
  if (t<64) Sxl[t] = ws[WS_SX + b*64 + t];
  __syncthreads();
  float sk = 0.f;
  #pragma unroll 4
  for (int c=0;c<64;++c) sk = fmaf(Gl[lane*67+c], Msub[o*65+c], sk);
  float d = Msub[o*65 + lane] * sk;
  float s1 = Msub[o*65 + lane] * Sxl[lane];
  #pragma unroll
  for (int off=1; off<64; off<<=1){
    d  += __shfl_xor(d,  off);
    s1 += __shfl_xor(s1, off);
  }
  if (lane==0){
    atomicAdd(&ws[WS_STATS + row], s1);
    atomicAdd(&ws[WS_STATS + 64 + row], d);
  }
}

// ---------------- KE v2: N rows + BN2 stats (R12-proven) ----------------
__global__ __launch_bounds__(256) void ke_n_stats2(const float* __restrict__ wl,
                                                   const float* __restrict__ g1,
                                                   float* __restrict__ ws){
  __shared__ float Ml[64*65];
  __shared__ float Gl[64*67];
  __shared__ float Nsub[4*65];
  __shared__ float Sxl[64], a1l[64];
  const int b = blockIdx.y, oq = blockIdx.x;
  const int t = threadIdx.x;
  const int o = t >> 6, lane = t & 63;
  const int row = oq*4 + o;
  if (t<64){
    const float mean1 = ws[WS_STATS+t]*INV_BL;
    const float var1 = ws[WS_STATS+64+t]*INV_BL - mean1*mean1;
    a1l[t] = g1[t]*rsqrtf(var1 + EPSV);
    Sxl[t] = ws[WS_SX + b*64 + t];
  }
  #pragma unroll
  for (int r=0;r<16;++r){
    const int e = t + 256*r;
    Ml[(e>>6)*65 + (e&63)] = ws[WS_M + b*4096 + e];
    Gl[(e>>6)*67 + (e&63)] = ws[WS_G + b*4096 + e];
  }
  __syncthreads();
  float acc = 0.f;
  #pragma unroll 4
  for (int k=0;k<64;++k){
    const float wk_ = wl[row*64 + k] * a1l[k];
    acc = fmaf(wk_, Ml[k*65 + lane], acc);
  }
  const float nv = acc + wl[row*64 + lane];
  ws[WS_N + b*4096 + row*64 + lane] = nv;
  Nsub[o*65 + lane] = nv;
  __syncthreads();
  float sk = 0.f;
  #pragma unroll 4
  for (int c=0;c<64;++c) sk = fmaf(Gl[lane*67+c], Nsub[o*65+c], sk);
  float d = Nsub[o*65 + lane] * sk;
  float s2 = Nsub[o*65 + lane] * Sxl[lane];
  #pragma unroll
  for (int off=1; off<64; off<<=1){
    d  += __shfl_xor(d,  off);
    s2 += __shfl_xor(s2, off);
  }
  if (lane==0){
    atomicAdd(&ws[WS_STATS + 128 + row], s2);
    atomicAdd(&ws[WS_STATS + 192 + row], d);
  }
}

// ---------------- K3 v3: 8 waves x 8 out-channels, no LDS, 4 waves/SIMD ----------------
// grid (32 lc, 16 b), 512 threads. Wave w owns out rows [8w, 8w+8).
__global__ __launch_bounds__(512) void k3_out(const float* __restrict__ x,
                                              const float* __restrict__ g2,
                                              const float* __restrict__ b2,
                                              const float* __restrict__ ws,
                                              float* __restrict__ out){
  __shared__ float a2l[64], el[64];
  const int b = blockIdx.y, lc = blockIdx.x;
  const int t = threadIdx.x;
  if (t<64){
    const float mu = ws[WS_STATS+128+t]*INV_BL;
    const float var2 = ws[WS_STATS+192+t]*INV_BL - mu*mu;
    const float a2 = g2[t]*rsqrtf(var2 + EPSV);
    a2l[t] = a2;
    el[t] = b2[t] - a2*mu;
  }
  __syncthreads();
  const int w = __builtin_amdgcn_readfirstlane(t >> 6);   // 0..7
  const int lane = t & 63;
  const int l = lc*256 + 4*lane;
  const float* Np = ws + WS_N + b*4096 + w*8*64;          // 8 rows, uniform -> s_load
  const float* xb = x + (size_t)b*TC*TL + l;
  float4 acc[8];
  #pragma unroll
  for (int oo=0;oo<8;++oo){ acc[oo].x=0.f; acc[oo].y=0.f; acc[oo].z=0.f; acc[oo].w=0.f; }
  #pragma unroll 8
  for (int c=0;c<64;++c){
    const float4 xv = *(const float4*)(xb + (size_t)c*TL);  // same addr all 8 waves -> L1
    #pragma unroll
    for (int oo=0;oo<8;++oo){
      const float nv = Np[oo*64 + c];
      acc[oo].x = fmaf(nv, xv.x, acc[oo].x);
      acc[oo].y = fmaf(nv, xv.y, acc[oo].y);
      acc[oo].z = fmaf(nv, xv.z, acc[oo].z);
      acc[oo].w = fmaf(nv, xv.w, acc[oo].w);
    }
  }
  #pragma unroll
  for (int oo=0;oo<8;++oo){
    const float a2v = a2l[w*8+oo], ev = el[w*8+oo];
    float4 r;
    r.x = fmaxf(fmaf(a2v, acc[oo].x, ev), 0.f);
    r.y = fmaxf(fmaf(a2v, acc[oo].y, ev), 0.f);
    r.z = fmaxf(fmaf(a2v, acc[oo].z, ev), 0.f);
    r.w = fmaxf(fmaf(a2v, acc[oo].w, ev), 0.f);
    *(float4*)(out + (size_t)(b*TC + w*8 + oo)*TL + l) = r;
  }
}

extern "C" void kernel_launch(void* const* d_in, const int* in_sizes, int n_in,
                              void* d_out, int out_size, void* d_ws, size_t ws_size,
                              hipStream_t stream){
  const float* x  = (const float*)d_in[0];
  const float* wk = (const float*)d_in[1];
  const float* wq = (const float*)d_in[2];
  const float* wv = (const float*)d_in[3];
  const float* wc = (const float*)d_in[4];
  const float* g1 = (const float*)d_in[5];
  /* b1 (d_in[6]) provably cancels through BN2 mean-subtraction */
  const float* wl = (const float*)d_in[7];
  const float* g2 = (const float*)d_in[8];
  const float* b2 = (const float*)d_in[9];
  float* out = (float*)d_out;
  float* ws  = (float*)d_ws;

  k1_gram    <<<dim3(64,16), 256, 0, stream>>>(x, ws);
  kA1        <<<dim3(16,16), 256, 0, stream>>>(ws);
  kA2        <<<dim3(4,16),  256, 0, stream>>>(wq, ws);
  kb12       <<<dim3(16,16), 256, 0, stream>>>(wk, wv, ws);
  kc_mpart   <<<dim3(16,16), 256, 0, stream>>>(wc, ws);
  kd_stats1  <<<dim3(16,16), 256, 0, stream>>>(ws);
  ke_n_stats2<<<dim3(16,16), 256, 0, stream>>>(wl, g1, ws);
  k3_out     <<<dim3(32,16), 512, 0, stream>>>(x, g2, b2, ws, out);
}